// Round 3
// baseline (895.682 us; speedup 1.0000x reference)
//
#include <hip/hip_runtime.h>

#define DEV __device__ __forceinline__

typedef __attribute__((ext_vector_type(8))) short short8;    // 8 bf16 (4 VGPRs)
typedef __attribute__((ext_vector_type(16))) float float16;  // MFMA 32x32 accumulator

// ---------- helpers ----------
DEV unsigned short f2bf(float x) {
    unsigned u = __float_as_uint(x);
    unsigned r = (u + 0x7FFFu + ((u >> 16) & 1u)) >> 16;
    return (unsigned short)r;
}
DEV unsigned pack_bf2(float a, float b) {
    return (unsigned)f2bf(a) | ((unsigned)f2bf(b) << 16);
}
DEV float bf2f(unsigned short v) {
    return __uint_as_float(((unsigned)v) << 16);
}
DEV float fastcos(float x) {  // cos(x), x in radians
    float r = x * 0.15915494309189535f;  // -> revolutions
    r = r - floorf(r);                   // [0,1)
    return __builtin_amdgcn_cosf(r);     // v_cos_f32: cos(2*pi*r)
}

// ---------- K0: build transposed / fragment-packed weights ----------
__global__ void prep_kernel(const float* __restrict__ W_user, const float* __restrict__ W_item,
                            const float* __restrict__ We_ui, const float* __restrict__ be_ui,
                            const float* __restrict__ We_iu, const float* __restrict__ be_iu,
                            const float* __restrict__ dW1, const float* __restrict__ dW2,
                            float* __restrict__ Wt_user, float* __restrict__ Wt_item,
                            unsigned short* __restrict__ Wb, float* __restrict__ bc,
                            float* __restrict__ W1t, float* __restrict__ W2t) {
    int t = threadIdx.x;
    for (int i = t; i < 1024; i += 256) {           // W[k][d] -> Wt[d][k], 32x32
        int k = i / 32, d = i % 32;
        Wt_user[d * 32 + k] = W_user[i];
        Wt_item[d * 32 + k] = W_item[i];
    }
    for (int i = t; i < 4096; i += 256) {           // MFMA B fragments (bf16)
        int kt   = i >> 10;          // k-tile 0..3
        int rem  = i & 1023;
        int n2   = rem >> 9;         // col-tile 0..1
        int rem2 = rem & 511;
        int l    = rem2 >> 3;        // lane 0..63
        int ii   = rem2 & 7;         // elem 0..7
        int k = kt * 16 + (l >> 5) * 8 + ii;
        int n = (l & 31);
        float v = n2 ? We_iu[k * 32 + n] : We_ui[k * 32 + n];
        Wb[i] = f2bf(v);
    }
    for (int i = t; i < 64; i += 256)
        bc[i] = (i < 32) ? be_ui[i] : be_iu[i - 32];
    for (int i = t; i < 4096; i += 256) {           // dec_W1[k][j] -> W1t[j][k], 64x64
        int j = i / 64, k = i % 64;
        W1t[i] = dW1[k * 64 + j];
    }
    for (int i = t; i < 1024; i += 256) {           // dec_W2[j][c] -> W2t[c][j], 16x64
        int c = i / 64, j = i % 64;
        W2t[i] = dW2[j * 16 + c];
    }
}

// ---------- K1: h = mem[ids] @ W, bf16 out (one thread per row) ----------
__global__ __launch_bounds__(256) void node_linear_kernel(
        const float* __restrict__ mem, const int* __restrict__ ids,
        const float* __restrict__ Wt, unsigned short* __restrict__ h, int B) {
    int r = blockIdx.x * 256 + threadIdx.x;
    if (r >= B) return;
    int id = ids[r];
    const float4* m4 = (const float4*)(mem + (size_t)id * 32);
    float m[32];
#pragma unroll
    for (int q = 0; q < 8; ++q) {
        float4 v = m4[q];
        m[4 * q + 0] = v.x; m[4 * q + 1] = v.y; m[4 * q + 2] = v.z; m[4 * q + 3] = v.w;
    }
    float o32[32];
    for (int db = 0; db < 8; ++db) {
#pragma unroll
        for (int u = 0; u < 4; ++u) {
            const float* wr = Wt + (size_t)(db * 4 + u) * 32;
            float a = 0.f;
#pragma unroll
            for (int k = 0; k < 32; ++k) a = fmaf(m[k], wr[k], a);
            o32[db * 4 + u] = a;
        }
    }
    uint4* hr = (uint4*)(h + (size_t)r * 32);
#pragma unroll
    for (int q = 0; q < 4; ++q) {
        uint4 p;
        p.x = pack_bf2(o32[8 * q + 0], o32[8 * q + 1]);
        p.y = pack_bf2(o32[8 * q + 2], o32[8 * q + 3]);
        p.z = pack_bf2(o32[8 * q + 4], o32[8 * q + 5]);
        p.w = pack_bf2(o32[8 * q + 6], o32[8 * q + 7]);
        hr[q] = p;
    }
}

// ---------- K2: proj = feat @ [We_ui|We_iu] + bias, bf16 out — MFMA ----------
__global__ __launch_bounds__(256) void proj_mfma_kernel(
        const float* __restrict__ feat, const unsigned short* __restrict__ Wb,
        const float* __restrict__ bc, unsigned short* __restrict__ proj, int NE) {
    __shared__ unsigned short lds[128 * 72];
    const int lane = threadIdx.x & 63;
    const int wave = threadIdx.x >> 6;
    const int col  = lane & 31;
    const int half = lane >> 5;

    short8 bfrag[8];
    const short8* wb8 = (const short8*)Wb;
#pragma unroll
    for (int f = 0; f < 8; ++f) bfrag[f] = wb8[f * 64 + lane];

    int r = blockIdx.x * 128 + wave * 32 + col;
    if (r >= NE) r = NE - 1;  // clamp; stores guarded below
    const float* fr = feat + (size_t)r * 64 + half * 8;
    short8 afrag[4];
#pragma unroll
    for (int t = 0; t < 4; ++t) {
        float4 a = *(const float4*)(fr + t * 16);
        float4 b = *(const float4*)(fr + t * 16 + 4);
        short8 s;
        s[0] = (short)f2bf(a.x); s[1] = (short)f2bf(a.y);
        s[2] = (short)f2bf(a.z); s[3] = (short)f2bf(a.w);
        s[4] = (short)f2bf(b.x); s[5] = (short)f2bf(b.y);
        s[6] = (short)f2bf(b.z); s[7] = (short)f2bf(b.w);
        afrag[t] = s;
    }

    float16 acc0, acc1;
    float b0 = bc[col], b1 = bc[32 + col];
#pragma unroll
    for (int i = 0; i < 16; ++i) { acc0[i] = b0; acc1[i] = b1; }
#pragma unroll
    for (int t = 0; t < 4; ++t) {
        acc0 = __builtin_amdgcn_mfma_f32_32x32x16_bf16(afrag[t], bfrag[t * 2 + 0], acc0, 0, 0, 0);
        acc1 = __builtin_amdgcn_mfma_f32_32x32x16_bf16(afrag[t], bfrag[t * 2 + 1], acc1, 0, 0, 0);
    }

#pragma unroll
    for (int reg = 0; reg < 16; ++reg) {
        int rl = wave * 32 + (reg & 3) + 8 * (reg >> 2) + 4 * half;
        lds[rl * 72 + col]      = f2bf(acc0[reg]);
        lds[rl * 72 + 32 + col] = f2bf(acc1[reg]);
    }
    __syncthreads();

    int trow = threadIdx.x >> 1, thalf = threadIdx.x & 1;
    int grow = blockIdx.x * 128 + trow;
    if (grow < NE) {
        const uint4* lsrc = (const uint4*)(lds + trow * 72 + thalf * 32);
        uint4* gdst = (uint4*)(proj + (size_t)grow * 64 + thalf * 32);
#pragma unroll
        for (int s = 0; s < 4; ++s) gdst[s] = lsrc[s];
    }
}

// ---------- K3a: histogram of destinations (both edge types) ----------
__global__ __launch_bounds__(256) void hist_kernel(
        const int* __restrict__ dst_ui, const int* __restrict__ dst_iu,
        int* __restrict__ cnt, int E, int B) {
    int i = blockIdx.x * 256 + threadIdx.x;
    if (i < E) atomicAdd(&cnt[dst_ui[i]], 1);
    else       atomicAdd(&cnt[B + dst_iu[i - E]], 1);
}

// ---------- K3b: scan, phase A — per-block exclusive scan of cnt[2B] ----------
__global__ __launch_bounds__(256) void scanA_kernel(
        const int* __restrict__ cnt, int* __restrict__ off, int* __restrict__ bsum) {
    __shared__ int s[256];
    int t = threadIdx.x;
    int i = blockIdx.x * 256 + t;
    int v = cnt[i];
    s[t] = v; __syncthreads();
#pragma unroll
    for (int o = 1; o < 256; o <<= 1) {
        int x = (t >= o) ? s[t - o] : 0;
        __syncthreads();
        s[t] += x;
        __syncthreads();
    }
    off[i] = s[t] - v;                 // block-local exclusive
    if (t == 255) bsum[blockIdx.x] = s[255];
}

// ---------- K3c: scan, phase B — scan 2048 block sums (two independent 1024-segments) ----------
__global__ __launch_bounds__(256) void scanB_kernel(
        const int* __restrict__ bsum, int* __restrict__ bscan) {
    __shared__ int s[256];
    int t = threadIdx.x;
    for (int seg = 0; seg < 2; ++seg) {
        int base = seg * 1024;
        int v[4]; int tot = 0;
#pragma unroll
        for (int k = 0; k < 4; ++k) { v[k] = bsum[base + t * 4 + k]; tot += v[k]; }
        s[t] = tot; __syncthreads();
#pragma unroll
        for (int o = 1; o < 256; o <<= 1) {
            int x = (t >= o) ? s[t - o] : 0;
            __syncthreads();
            s[t] += x;
            __syncthreads();
        }
        int run = s[t] - tot;          // exclusive across threads
#pragma unroll
        for (int k = 0; k < 4; ++k) { bscan[base + t * 4 + k] = run; run += v[k]; }
        __syncthreads();
    }
}

// ---------- K3d: scan, phase C — add block bases; emit off and cursor copy ----------
__global__ __launch_bounds__(256) void scanC_kernel(
        int* __restrict__ off, const int* __restrict__ bscan, int* __restrict__ cur) {
    int i = blockIdx.x * 256 + threadIdx.x;
    int o = off[i] + bscan[blockIdx.x];
    off[i] = o;
    cur[i] = o;
}

// ---------- K3e: permute edges into dst-sorted (CSR) order, both types ----------
__global__ __launch_bounds__(256) void permute_kernel(
        const int* __restrict__ src_ui, const int* __restrict__ dst_ui,
        const int* __restrict__ eidx_ui, const float* __restrict__ rt_ui,
        const int* __restrict__ src_iu, const int* __restrict__ dst_iu,
        const int* __restrict__ eidx_iu, const float* __restrict__ rt_iu,
        int* __restrict__ cur,
        int* __restrict__ ssrc_ui, int* __restrict__ seidx_ui, float* __restrict__ srt_ui,
        int* __restrict__ ssrc_iu, int* __restrict__ seidx_iu, float* __restrict__ srt_iu,
        int E, int B) {
    int i = blockIdx.x * 256 + threadIdx.x;
    if (i < E) {
        int b = dst_ui[i];
        int p = atomicAdd(&cur[b], 1);
        ssrc_ui[p] = src_ui[i]; seidx_ui[p] = eidx_ui[i]; srt_ui[p] = rt_ui[i];
    } else {
        int k = i - E;
        int b = dst_iu[k];
        int p = atomicAdd(&cur[B + b], 1);
        ssrc_iu[p] = src_iu[k]; seidx_iu[p] = eidx_iu[k]; srt_iu[p] = rt_iu[k];
    }
}

// ---------- K3f: gather-aggregate per dst (32 lanes per dst, no atomics) ----------
// out[b] = relu(h_self[b] + sum_j (h_src[src_j] + proj[eidx_j] + cos(t_j*w+b)))
__global__ __launch_bounds__(256) void gather_kernel(
        const unsigned short* __restrict__ h_src, const unsigned short* __restrict__ h_self,
        const unsigned short* __restrict__ proj,   // pre-offset to the right 32-col half
        const int* __restrict__ ssrc, const int* __restrict__ seidx, const float* __restrict__ srt,
        const int* __restrict__ off, const int* __restrict__ cur,
        const float* __restrict__ tw, const float* __restrict__ tb,
        float* __restrict__ outz) {
    int g = (blockIdx.x * 256 + threadIdx.x) >> 5;   // dst node
    int d = threadIdx.x & 31;
    int start = off[g], end = cur[g];
    float twd = tw[d], tbd = tb[d];
    float acc = 0.f;
    int j = start;
    for (; j + 2 <= end; j += 2) {   // 2-edge unroll for memory ILP
        int s0 = ssrc[j],  s1 = ssrc[j + 1];
        int e0 = seidx[j], e1 = seidx[j + 1];
        float t0 = srt[j], t1 = srt[j + 1];
        float hv0 = bf2f(h_src[(size_t)s0 * 32 + d]);
        float hv1 = bf2f(h_src[(size_t)s1 * 32 + d]);
        float p0 = bf2f(proj[(size_t)e0 * 64 + d]);
        float p1 = bf2f(proj[(size_t)e1 * 64 + d]);
        acc += hv0 + p0 + fastcos(fmaf(t0, twd, tbd));
        acc += hv1 + p1 + fastcos(fmaf(t1, twd, tbd));
    }
    if (j < end) {
        int s0 = ssrc[j]; int e0 = seidx[j]; float t0 = srt[j];
        acc += bf2f(h_src[(size_t)s0 * 32 + d]) + bf2f(proj[(size_t)e0 * 64 + d])
             + fastcos(fmaf(t0, twd, tbd));
    }
    float hs = bf2f(h_self[(size_t)g * 32 + d]);
    outz[(size_t)g * 32 + d] = fmaxf(hs + acc, 0.f);
}

// ---------- K4: decoder MLP on pre-relu'd hu/hi (one thread per row) ----------
__global__ __launch_bounds__(256) void decoder_kernel(
        const float* __restrict__ hu, const float* __restrict__ hi,
        const float* __restrict__ W1t, const float* __restrict__ b1,
        const float* __restrict__ W2t, const float* __restrict__ b2,
        const float* __restrict__ W3, const float* __restrict__ b3,
        float* __restrict__ out, int B) {
    int i = blockIdx.x * 256 + threadIdx.x;
    if (i >= B) return;
    float z[64];
    {
        const float4* a4 = (const float4*)(hu + (size_t)i * 32);
#pragma unroll
        for (int q = 0; q < 8; ++q) {
            float4 a = a4[q];
            z[4 * q + 0] = a.x; z[4 * q + 1] = a.y; z[4 * q + 2] = a.z; z[4 * q + 3] = a.w;
        }
    }
    {
        const float4* a4 = (const float4*)(hi + (size_t)i * 32);
#pragma unroll
        for (int q = 0; q < 8; ++q) {
            float4 a = a4[q];
            z[32 + 4 * q + 0] = a.x; z[32 + 4 * q + 1] = a.y;
            z[32 + 4 * q + 2] = a.z; z[32 + 4 * q + 3] = a.w;
        }
    }
    float x2[16];
#pragma unroll
    for (int c = 0; c < 16; ++c) x2[c] = b2[c];
    for (int jb = 0; jb < 8; ++jb) {
        float a[8];
#pragma unroll
        for (int u = 0; u < 8; ++u) {
            int j = jb * 8 + u;
            const float* wr = W1t + (size_t)j * 64;
            float acc = b1[j];
#pragma unroll
            for (int k = 0; k < 64; ++k) acc = fmaf(z[k], wr[k], acc);
            a[u] = fmaxf(acc, 0.f);
        }
#pragma unroll
        for (int c = 0; c < 16; ++c) {
            const float* w2r = W2t + (size_t)c * 64 + jb * 8;
            float acc = x2[c];
#pragma unroll
            for (int u = 0; u < 8; ++u) acc = fmaf(a[u], w2r[u], acc);
            x2[c] = acc;
        }
    }
    float o = b3[0];
#pragma unroll
    for (int c = 0; c < 16; ++c) o = fmaf(fmaxf(x2[c], 0.f), W3[c], o);
    out[i] = o;
}

extern "C" void kernel_launch(void* const* d_in, const int* in_sizes, int n_in,
                              void* d_out, int out_size, void* d_ws, size_t ws_size,
                              hipStream_t stream) {
    const float* mem_user = (const float*)d_in[0];
    const float* mem_item = (const float*)d_in[1];
    const int*   ids_user = (const int*)d_in[2];
    const int*   ids_item = (const int*)d_in[3];
    const int*   src_ui   = (const int*)d_in[4];
    const int*   dst_ui   = (const int*)d_in[5];
    const int*   src_iu   = (const int*)d_in[6];
    const int*   dst_iu   = (const int*)d_in[7];
    const int*   eidx_ui  = (const int*)d_in[8];
    const int*   eidx_iu  = (const int*)d_in[9];
    const float* rt_ui    = (const float*)d_in[10];
    const float* rt_iu    = (const float*)d_in[11];
    const float* feat     = (const float*)d_in[12];
    const float* W_user   = (const float*)d_in[13];
    const float* W_item   = (const float*)d_in[14];
    const float* We_ui    = (const float*)d_in[15];
    const float* be_ui    = (const float*)d_in[16];
    const float* We_iu    = (const float*)d_in[17];
    const float* be_iu    = (const float*)d_in[18];
    const float* tw       = (const float*)d_in[19];
    const float* tb       = (const float*)d_in[20];
    const float* dW1      = (const float*)d_in[21];
    const float* db1      = (const float*)d_in[22];
    const float* dW2      = (const float*)d_in[23];
    const float* db2      = (const float*)d_in[24];
    const float* dW3      = (const float*)d_in[25];
    const float* db3      = (const float*)d_in[26];

    const int B  = in_sizes[2];     // 262144
    const int E  = in_sizes[4];     // 1048576
    const int NE = in_sizes[12] / 64;  // 500000

    char* w = (char*)d_ws;
    const size_t hsz = (size_t)B * 32;
    float* hu = (float*)w;                        w += hsz * 4;
    float* hi = (float*)w;                        w += hsz * 4;
    unsigned short* h_user_bf = (unsigned short*)w; w += hsz * 2;
    unsigned short* h_item_bf = (unsigned short*)w; w += hsz * 2;
    unsigned short* proj = (unsigned short*)w;    w += (size_t)NE * 64 * 2;
    int*   ssrc_ui  = (int*)w;   w += (size_t)E * 4;
    int*   seidx_ui = (int*)w;   w += (size_t)E * 4;
    float* srt_ui   = (float*)w; w += (size_t)E * 4;
    int*   ssrc_iu  = (int*)w;   w += (size_t)E * 4;
    int*   seidx_iu = (int*)w;   w += (size_t)E * 4;
    float* srt_iu   = (float*)w; w += (size_t)E * 4;
    int*   cnt = (int*)w;  w += (size_t)2 * B * 4;   // reused as `off` in-place by scanA
    int*   cur = (int*)w;  w += (size_t)2 * B * 4;
    int*   off = (int*)w;  w += (size_t)2 * B * 4;
    int*   bsum  = (int*)w; w += 2048 * 4;
    int*   bscan = (int*)w; w += 2048 * 4;
    float* Wt_user = (float*)w; w += 1024 * 4;
    float* Wt_item = (float*)w; w += 1024 * 4;
    unsigned short* Wb = (unsigned short*)w; w += 4096 * 2;
    float* bc  = (float*)w; w += 64 * 4;
    float* W1t = (float*)w; w += 4096 * 4;
    float* W2t = (float*)w; w += 1024 * 4;

    prep_kernel<<<1, 256, 0, stream>>>(W_user, W_item, We_ui, be_ui, We_iu, be_iu, dW1, dW2,
                                       Wt_user, Wt_item, Wb, bc, W1t, W2t);
    node_linear_kernel<<<B / 256, 256, 0, stream>>>(mem_user, ids_user, Wt_user, h_user_bf, B);
    node_linear_kernel<<<B / 256, 256, 0, stream>>>(mem_item, ids_item, Wt_item, h_item_bf, B);
    proj_mfma_kernel<<<(NE + 127) / 128, 256, 0, stream>>>(feat, Wb, bc, proj, NE);

    // CSR build
    hipMemsetAsync(cnt, 0, (size_t)2 * B * 4, stream);
    hist_kernel<<<2 * E / 256, 256, 0, stream>>>(dst_ui, dst_iu, cnt, E, B);
    scanA_kernel<<<2 * B / 256, 256, 0, stream>>>(cnt, off, bsum);
    scanB_kernel<<<1, 256, 0, stream>>>(bsum, bscan);
    scanC_kernel<<<2 * B / 256, 256, 0, stream>>>(off, bscan, cur);
    permute_kernel<<<2 * E / 256, 256, 0, stream>>>(src_ui, dst_ui, eidx_ui, rt_ui,
                                                    src_iu, dst_iu, eidx_iu, rt_iu,
                                                    cur,
                                                    ssrc_ui, seidx_ui, srt_ui,
                                                    ssrc_iu, seidx_iu, srt_iu, E, B);

    // gather-aggregate (no atomics): hi from ui edges, hu from iu edges
    gather_kernel<<<B * 32 / 256, 256, 0, stream>>>(h_user_bf, h_item_bf, proj + 0,
                                                    ssrc_ui, seidx_ui, srt_ui,
                                                    off, cur, tw, tb, hi);
    gather_kernel<<<B * 32 / 256, 256, 0, stream>>>(h_item_bf, h_user_bf, proj + 32,
                                                    ssrc_iu, seidx_iu, srt_iu,
                                                    off + B, cur + B, tw, tb, hu);

    decoder_kernel<<<B / 256, 256, 0, stream>>>(hu, hi, W1t, db1, W2t, db2, dW3, db3,
                                                (float*)d_out, B);
}

// Round 4
// 864.960 us; speedup vs baseline: 1.0355x; 1.0355x over previous
//
#include <hip/hip_runtime.h>

#define DEV __device__ __forceinline__

typedef __attribute__((ext_vector_type(8))) short short8;    // 8 bf16 (4 VGPRs)
typedef __attribute__((ext_vector_type(16))) float float16;  // MFMA 32x32 accumulator

// ---------- helpers ----------
DEV unsigned short f2bf(float x) {
    unsigned u = __float_as_uint(x);
    unsigned r = (u + 0x7FFFu + ((u >> 16) & 1u)) >> 16;
    return (unsigned short)r;
}
DEV unsigned pack_bf2(float a, float b) {
    return (unsigned)f2bf(a) | ((unsigned)f2bf(b) << 16);
}
DEV float bf2f(unsigned short v) {
    return __uint_as_float(((unsigned)v) << 16);
}
DEV float fastcos(float x) {  // cos(x), x in radians
    float r = x * 0.15915494309189535f;  // -> revolutions
    r = r - floorf(r);                   // [0,1)
    return __builtin_amdgcn_cosf(r);     // v_cos_f32: cos(2*pi*r)
}

// ---------- K0: build transposed / fragment-packed weights ----------
__global__ void prep_kernel(const float* __restrict__ W_user, const float* __restrict__ W_item,
                            const float* __restrict__ We_ui, const float* __restrict__ be_ui,
                            const float* __restrict__ We_iu, const float* __restrict__ be_iu,
                            const float* __restrict__ dW1, const float* __restrict__ dW2,
                            float* __restrict__ Wt_user, float* __restrict__ Wt_item,
                            unsigned short* __restrict__ Wb, float* __restrict__ bc,
                            float* __restrict__ W1t, float* __restrict__ W2t) {
    int t = threadIdx.x;
    for (int i = t; i < 1024; i += 256) {           // W[k][d] -> Wt[d][k], 32x32
        int k = i / 32, d = i % 32;
        Wt_user[d * 32 + k] = W_user[i];
        Wt_item[d * 32 + k] = W_item[i];
    }
    for (int i = t; i < 4096; i += 256) {           // MFMA B fragments (bf16)
        int kt   = i >> 10;          // k-tile 0..3
        int rem  = i & 1023;
        int n2   = rem >> 9;         // col-tile 0..1 (0=ui, 1=iu)
        int rem2 = rem & 511;
        int l    = rem2 >> 3;        // lane 0..63
        int ii   = rem2 & 7;         // elem 0..7
        int k = kt * 16 + (l >> 5) * 8 + ii;
        int n = (l & 31);
        float v = n2 ? We_iu[k * 32 + n] : We_ui[k * 32 + n];
        Wb[i] = f2bf(v);
    }
    for (int i = t; i < 64; i += 256)
        bc[i] = (i < 32) ? be_ui[i] : be_iu[i - 32];
    for (int i = t; i < 4096; i += 256) {           // dec_W1[k][j] -> W1t[j][k], 64x64
        int j = i / 64, k = i % 64;
        W1t[i] = dW1[k * 64 + j];
    }
    for (int i = t; i < 1024; i += 256) {           // dec_W2[j][c] -> W2t[c][j], 16x64
        int c = i / 64, j = i % 64;
        W2t[i] = dW2[j * 16 + c];
    }
}

// ---------- K1: h = mem[ids] @ W, bf16 out (one thread per row) ----------
__global__ __launch_bounds__(256) void node_linear_kernel(
        const float* __restrict__ mem, const int* __restrict__ ids,
        const float* __restrict__ Wt, unsigned short* __restrict__ h, int B) {
    int r = blockIdx.x * 256 + threadIdx.x;
    if (r >= B) return;
    int id = ids[r];
    const float4* m4 = (const float4*)(mem + (size_t)id * 32);
    float m[32];
#pragma unroll
    for (int q = 0; q < 8; ++q) {
        float4 v = m4[q];
        m[4 * q + 0] = v.x; m[4 * q + 1] = v.y; m[4 * q + 2] = v.z; m[4 * q + 3] = v.w;
    }
    float o32[32];
    for (int db = 0; db < 8; ++db) {
#pragma unroll
        for (int u = 0; u < 4; ++u) {
            const float* wr = Wt + (size_t)(db * 4 + u) * 32;
            float a = 0.f;
#pragma unroll
            for (int k = 0; k < 32; ++k) a = fmaf(m[k], wr[k], a);
            o32[db * 4 + u] = a;
        }
    }
    uint4* hr = (uint4*)(h + (size_t)r * 32);
#pragma unroll
    for (int q = 0; q < 4; ++q) {
        uint4 p;
        p.x = pack_bf2(o32[8 * q + 0], o32[8 * q + 1]);
        p.y = pack_bf2(o32[8 * q + 2], o32[8 * q + 3]);
        p.z = pack_bf2(o32[8 * q + 4], o32[8 * q + 5]);
        p.w = pack_bf2(o32[8 * q + 6], o32[8 * q + 7]);
        hr[q] = p;
    }
}

// ---------- K2: proj planes = feat @ We_* + bias, bf16 out — MFMA ----------
// acc0 -> proj_ui[r][0:32], acc1 -> proj_iu[r][0:32] (separate 32-col planes so the
// edge gather fetches only useful bytes).
__global__ __launch_bounds__(256) void proj_mfma_kernel(
        const float* __restrict__ feat, const unsigned short* __restrict__ Wb,
        const float* __restrict__ bc,
        unsigned short* __restrict__ proj_ui, unsigned short* __restrict__ proj_iu, int NE) {
    __shared__ unsigned short lds[128 * 72];
    const int lane = threadIdx.x & 63;
    const int wave = threadIdx.x >> 6;
    const int col  = lane & 31;
    const int half = lane >> 5;

    short8 bfrag[8];
    const short8* wb8 = (const short8*)Wb;
#pragma unroll
    for (int f = 0; f < 8; ++f) bfrag[f] = wb8[f * 64 + lane];

    int r = blockIdx.x * 128 + wave * 32 + col;
    if (r >= NE) r = NE - 1;  // clamp; stores guarded below
    const float* fr = feat + (size_t)r * 64 + half * 8;
    short8 afrag[4];
#pragma unroll
    for (int t = 0; t < 4; ++t) {
        float4 a = *(const float4*)(fr + t * 16);
        float4 b = *(const float4*)(fr + t * 16 + 4);
        short8 s;
        s[0] = (short)f2bf(a.x); s[1] = (short)f2bf(a.y);
        s[2] = (short)f2bf(a.z); s[3] = (short)f2bf(a.w);
        s[4] = (short)f2bf(b.x); s[5] = (short)f2bf(b.y);
        s[6] = (short)f2bf(b.z); s[7] = (short)f2bf(b.w);
        afrag[t] = s;
    }

    float16 acc0, acc1;
    float b0 = bc[col], b1 = bc[32 + col];
#pragma unroll
    for (int i = 0; i < 16; ++i) { acc0[i] = b0; acc1[i] = b1; }
#pragma unroll
    for (int t = 0; t < 4; ++t) {
        acc0 = __builtin_amdgcn_mfma_f32_32x32x16_bf16(afrag[t], bfrag[t * 2 + 0], acc0, 0, 0, 0);
        acc1 = __builtin_amdgcn_mfma_f32_32x32x16_bf16(afrag[t], bfrag[t * 2 + 1], acc1, 0, 0, 0);
    }

    // C/D: col = lane&31, row = (reg&3) + 8*(reg>>2) + 4*(lane>>5)
#pragma unroll
    for (int reg = 0; reg < 16; ++reg) {
        int rl = wave * 32 + (reg & 3) + 8 * (reg >> 2) + 4 * half;
        lds[rl * 72 + col]      = f2bf(acc0[reg]);
        lds[rl * 72 + 32 + col] = f2bf(acc1[reg]);
    }
    __syncthreads();

    // writer: thread -> (row = tid>>1, plane = tid&1), 64B per row-plane
    int trow = threadIdx.x >> 1, tpl = threadIdx.x & 1;
    int grow = blockIdx.x * 128 + trow;
    if (grow < NE) {
        const uint4* lsrc = (const uint4*)(lds + trow * 72 + tpl * 32);
        unsigned short* gp = (tpl ? proj_iu : proj_ui) + (size_t)grow * 32;
        uint4* gdst = (uint4*)gp;
#pragma unroll
        for (int s = 0; s < 4; ++s) gdst[s] = lsrc[s];
    }
}

// ---------- K3a: bucket histogram (64 buckets: 0-31 ui, 32-63 iu) ----------
// bucket = dst >> 13 (8192 dst rows = 1 MB of agg per bucket)
__global__ __launch_bounds__(256) void hist_kernel(
        const int* __restrict__ dst_ui, const int* __restrict__ dst_iu,
        int* __restrict__ gcnt, int E) {
    __shared__ int cnt[64];
    int t = threadIdx.x;
    if (t < 64) cnt[t] = 0;
    __syncthreads();
    long long chunk = (long long)blockIdx.x * 2048;
#pragma unroll
    for (int k = 0; k < 8; ++k) {
        long long i = chunk + t + k * 256;
        int b;
        if (i < E) b = dst_ui[i] >> 13;
        else       b = 32 + (dst_iu[i - E] >> 13);
        atomicAdd(&cnt[b], 1);
    }
    __syncthreads();
    if (t < 64) atomicAdd(&gcnt[t], cnt[t]);
}

// ---------- K3b: tiny scan (two independent 32-bucket segments) ----------
__global__ void scan_kernel(const int* __restrict__ gcnt,
                            int* __restrict__ gcur, int* __restrict__ bstart) {
    if (threadIdx.x == 0) {
        int acc = 0;
        for (int b = 0; b < 32; ++b) { bstart[b] = acc; gcur[b] = acc; acc += gcnt[b]; }
        acc = 0;
        for (int b = 32; b < 64; ++b) { bstart[b] = acc; gcur[b] = acc; acc += gcnt[b]; }
    }
}

// ---------- K3c: append packed records into coarse buckets ----------
// Per block: LDS hist of its 2048 edges, one reserved global range per bucket,
// then write (dst,src,eidx,rt) int4 records into block-private contiguous runs.
__global__ __launch_bounds__(256) void append_kernel(
        const int* __restrict__ dst_ui, const int* __restrict__ src_ui,
        const int* __restrict__ eidx_ui, const float* __restrict__ rt_ui,
        const int* __restrict__ dst_iu, const int* __restrict__ src_iu,
        const int* __restrict__ eidx_iu, const float* __restrict__ rt_iu,
        int* __restrict__ gcur, int4* __restrict__ recs_ui, int4* __restrict__ recs_iu, int E) {
    __shared__ int cnt[64], gbase[64], lcur[64];
    int t = threadIdx.x;
    if (t < 64) { cnt[t] = 0; lcur[t] = 0; }
    __syncthreads();
    long long chunk = (long long)blockIdx.x * 2048;
    int4 r[8]; int bb[8];
#pragma unroll
    for (int k = 0; k < 8; ++k) {
        long long i = chunk + t + k * 256;
        int4 v; int b;
        if (i < E) {
            v.x = dst_ui[i]; v.y = src_ui[i]; v.z = eidx_ui[i];
            v.w = __float_as_int(rt_ui[i]);
            b = v.x >> 13;
        } else {
            long long q = i - E;
            v.x = dst_iu[q]; v.y = src_iu[q]; v.z = eidx_iu[q];
            v.w = __float_as_int(rt_iu[q]);
            b = 32 + (v.x >> 13);
        }
        r[k] = v; bb[k] = b;
        atomicAdd(&cnt[b], 1);
    }
    __syncthreads();
    if (t < 64) gbase[t] = atomicAdd(&gcur[t], cnt[t]);
    __syncthreads();
#pragma unroll
    for (int k = 0; k < 8; ++k) {
        int b = bb[k];
        int p = gbase[b] + atomicAdd(&lcur[b], 1);
        if (b < 32) recs_ui[p] = r[k];
        else        recs_iu[p] = r[k];
    }
}

// ---------- K3d: bucket-ordered edge processing, L2-resident atomics ----------
// 2048 blocks; block -> xcd = blockIdx&7 (locality heuristic only). Each xcd-group
// processes buckets xcd, xcd+8, ... so each XCD's L2 mostly sees a 1 MB agg slice.
__global__ __launch_bounds__(256) void edge_bucket_kernel(
        const int4* __restrict__ recs, const unsigned short* __restrict__ h_src,
        const unsigned short* __restrict__ projT, float* __restrict__ agg,
        const float* __restrict__ tw, const float* __restrict__ tb,
        const int* __restrict__ bstart, const int* __restrict__ gcur, int bkoff) {
    const int d = threadIdx.x & 31;
    const int group = threadIdx.x >> 5;       // 0..7
    const int xcd = blockIdx.x & 7, bslot = blockIdx.x >> 3;  // 256 slots
    const float twd = tw[d], tbd = tb[d];
    const int RUN = 64;
    for (int bk = xcd; bk < 32; bk += 8) {
        const int s = bstart[bkoff + bk], e = gcur[bkoff + bk];
        for (int j0 = s + (bslot * 8 + group) * RUN; j0 < e; j0 += 256 * 8 * RUN) {
            int je = min(e, j0 + RUN);
#pragma unroll 2
            for (int j = j0; j < je; ++j) {
                int4 r = recs[j];   // same addr across the 32-lane group -> broadcast, L1-hot
                float hv = bf2f(h_src[(size_t)r.y * 32 + d]);
                float pv = bf2f(projT[(size_t)r.z * 32 + d]);
                float c = fastcos(fmaf(__int_as_float(r.w), twd, tbd));
                unsafeAtomicAdd(&agg[(size_t)r.x * 32 + d], hv + pv + c);
            }
        }
    }
}

// ---------- K4: decoder MLP with fused relu(h+agg) (one thread per row) ----------
__global__ __launch_bounds__(256) void decoder_kernel(
        const unsigned short* __restrict__ h_user, const unsigned short* __restrict__ h_item,
        const float* __restrict__ agg_user, const float* __restrict__ agg_item,
        const float* __restrict__ W1t, const float* __restrict__ b1,
        const float* __restrict__ W2t, const float* __restrict__ b2,
        const float* __restrict__ W3, const float* __restrict__ b3,
        float* __restrict__ out, int B) {
    int i = blockIdx.x * 256 + threadIdx.x;
    if (i >= B) return;
    float z[64];
    {
        const uint4* h4 = (const uint4*)(h_user + (size_t)i * 32);
        const float4* a4 = (const float4*)(agg_user + (size_t)i * 32);
#pragma unroll
        for (int q = 0; q < 4; ++q) {
            uint4 hp = h4[q];
            float4 a0 = a4[2 * q], a1 = a4[2 * q + 1];
            unsigned hw[4] = {hp.x, hp.y, hp.z, hp.w};
            float av[8] = {a0.x, a0.y, a0.z, a0.w, a1.x, a1.y, a1.z, a1.w};
#pragma unroll
            for (int u = 0; u < 4; ++u) {
                float lo = __uint_as_float(hw[u] << 16);
                float hi2 = __uint_as_float(hw[u] & 0xFFFF0000u);
                z[8 * q + 2 * u]     = fmaxf(lo + av[2 * u], 0.f);
                z[8 * q + 2 * u + 1] = fmaxf(hi2 + av[2 * u + 1], 0.f);
            }
        }
    }
    {
        const uint4* h4 = (const uint4*)(h_item + (size_t)i * 32);
        const float4* a4 = (const float4*)(agg_item + (size_t)i * 32);
#pragma unroll
        for (int q = 0; q < 4; ++q) {
            uint4 hp = h4[q];
            float4 a0 = a4[2 * q], a1 = a4[2 * q + 1];
            unsigned hw[4] = {hp.x, hp.y, hp.z, hp.w};
            float av[8] = {a0.x, a0.y, a0.z, a0.w, a1.x, a1.y, a1.z, a1.w};
#pragma unroll
            for (int u = 0; u < 4; ++u) {
                float lo = __uint_as_float(hw[u] << 16);
                float hi2 = __uint_as_float(hw[u] & 0xFFFF0000u);
                z[32 + 8 * q + 2 * u]     = fmaxf(lo + av[2 * u], 0.f);
                z[32 + 8 * q + 2 * u + 1] = fmaxf(hi2 + av[2 * u + 1], 0.f);
            }
        }
    }
    float x2[16];
#pragma unroll
    for (int c = 0; c < 16; ++c) x2[c] = b2[c];
    for (int jb = 0; jb < 8; ++jb) {
        float a[8];
#pragma unroll
        for (int u = 0; u < 8; ++u) {
            int j = jb * 8 + u;
            const float* wr = W1t + (size_t)j * 64;
            float acc = b1[j];
#pragma unroll
            for (int k = 0; k < 64; ++k) acc = fmaf(z[k], wr[k], acc);
            a[u] = fmaxf(acc, 0.f);
        }
#pragma unroll
        for (int c = 0; c < 16; ++c) {
            const float* w2r = W2t + (size_t)c * 64 + jb * 8;
            float acc = x2[c];
#pragma unroll
            for (int u = 0; u < 8; ++u) acc = fmaf(a[u], w2r[u], acc);
            x2[c] = acc;
        }
    }
    float o = b3[0];
#pragma unroll
    for (int c = 0; c < 16; ++c) o = fmaf(fmaxf(x2[c], 0.f), W3[c], o);
    out[i] = o;
}

extern "C" void kernel_launch(void* const* d_in, const int* in_sizes, int n_in,
                              void* d_out, int out_size, void* d_ws, size_t ws_size,
                              hipStream_t stream) {
    const float* mem_user = (const float*)d_in[0];
    const float* mem_item = (const float*)d_in[1];
    const int*   ids_user = (const int*)d_in[2];
    const int*   ids_item = (const int*)d_in[3];
    const int*   src_ui   = (const int*)d_in[4];
    const int*   dst_ui   = (const int*)d_in[5];
    const int*   src_iu   = (const int*)d_in[6];
    const int*   dst_iu   = (const int*)d_in[7];
    const int*   eidx_ui  = (const int*)d_in[8];
    const int*   eidx_iu  = (const int*)d_in[9];
    const float* rt_ui    = (const float*)d_in[10];
    const float* rt_iu    = (const float*)d_in[11];
    const float* feat     = (const float*)d_in[12];
    const float* W_user   = (const float*)d_in[13];
    const float* W_item   = (const float*)d_in[14];
    const float* We_ui    = (const float*)d_in[15];
    const float* be_ui    = (const float*)d_in[16];
    const float* We_iu    = (const float*)d_in[17];
    const float* be_iu    = (const float*)d_in[18];
    const float* tw       = (const float*)d_in[19];
    const float* tb       = (const float*)d_in[20];
    const float* dW1      = (const float*)d_in[21];
    const float* db1      = (const float*)d_in[22];
    const float* dW2      = (const float*)d_in[23];
    const float* db2      = (const float*)d_in[24];
    const float* dW3      = (const float*)d_in[25];
    const float* db3      = (const float*)d_in[26];

    const int B  = in_sizes[2];        // 262144
    const int E  = in_sizes[4];        // 1048576
    const int NE = in_sizes[12] / 64;  // 500000

    char* w = (char*)d_ws;
    const size_t hsz = (size_t)B * 32;
    unsigned short* h_user_bf = (unsigned short*)w; w += hsz * 2;          // 16 MB
    unsigned short* h_item_bf = (unsigned short*)w; w += hsz * 2;          // 16 MB
    unsigned short* proj_ui = (unsigned short*)w;   w += (size_t)NE * 32 * 2;  // 32 MB
    unsigned short* proj_iu = (unsigned short*)w;   w += (size_t)NE * 32 * 2;  // 32 MB
    int4* recs_ui = (int4*)w;  w += (size_t)E * 16;                        // 16 MB
    int4* recs_iu = (int4*)w;  w += (size_t)E * 16;                        // 16 MB
    float* agg_user = (float*)w; w += hsz * 4;                             // 32 MB
    float* agg_item = (float*)w; w += hsz * 4;                             // 32 MB
    int* gcnt   = (int*)w; w += 64 * 4;
    int* gcur   = (int*)w; w += 64 * 4;
    int* bstart = (int*)w; w += 64 * 4;
    float* Wt_user = (float*)w; w += 1024 * 4;
    float* Wt_item = (float*)w; w += 1024 * 4;
    unsigned short* Wb = (unsigned short*)w; w += 4096 * 2;
    float* bc  = (float*)w; w += 64 * 4;
    float* W1t = (float*)w; w += 4096 * 4;
    float* W2t = (float*)w; w += 1024 * 4;

    prep_kernel<<<1, 256, 0, stream>>>(W_user, W_item, We_ui, be_ui, We_iu, be_iu, dW1, dW2,
                                       Wt_user, Wt_item, Wb, bc, W1t, W2t);
    node_linear_kernel<<<B / 256, 256, 0, stream>>>(mem_user, ids_user, Wt_user, h_user_bf, B);
    node_linear_kernel<<<B / 256, 256, 0, stream>>>(mem_item, ids_item, Wt_item, h_item_bf, B);
    proj_mfma_kernel<<<(NE + 127) / 128, 256, 0, stream>>>(feat, Wb, bc, proj_ui, proj_iu, NE);

    // coarse 32-bucket sort of both edge lists into packed int4 records
    hipMemsetAsync(gcnt, 0, 64 * 4, stream);
    int nchunks = (2 * E + 2047) / 2048;
    hist_kernel<<<nchunks, 256, 0, stream>>>(dst_ui, dst_iu, gcnt, E);
    scan_kernel<<<1, 64, 0, stream>>>(gcnt, gcur, bstart);
    append_kernel<<<nchunks, 256, 0, stream>>>(dst_ui, src_ui, eidx_ui, rt_ui,
                                               dst_iu, src_iu, eidx_iu, rt_iu,
                                               gcur, recs_ui, recs_iu, E);

    // bucket-ordered scatter-add (agg slices stay L2-resident)
    hipMemsetAsync(agg_user, 0, 2 * hsz * 4, stream);  // agg_user+agg_item contiguous
    edge_bucket_kernel<<<2048, 256, 0, stream>>>(recs_ui, h_user_bf, proj_ui, agg_item,
                                                 tw, tb, bstart, gcur, 0);
    edge_bucket_kernel<<<2048, 256, 0, stream>>>(recs_iu, h_item_bf, proj_iu, agg_user,
                                                 tw, tb, bstart, gcur, 32);

    decoder_kernel<<<B / 256, 256, 0, stream>>>(h_user_bf, h_item_bf, agg_user, agg_item,
                                                W1t, db1, W2t, db2, dW3, db3,
                                                (float*)d_out, B);
}